// Round 11
// baseline (166.497 us; speedup 1.0000x reference)
//
#include <hip/hip_runtime.h>

namespace {
constexpr float SCALE = 0.17677669529663687f; // 32^-0.5

typedef const __attribute__((address_space(1))) void gbl_v;
typedef __attribute__((address_space(3))) void lds_v;
typedef float v2f __attribute__((ext_vector_type(2)));   // -> v_pk_fma_f32

// quad_perm DPP xor-permute (VALU, no LDS pipe): 0xB1 = lane^1, 0x4E = lane^2
template<int CTRL>
__device__ __forceinline__ float qperm(float v) {
  return __builtin_bit_cast(float, __builtin_amdgcn_mov_dpp(
      __builtin_bit_cast(int, v), CTRL, 0xF, 0xF, true));
}

#define FENCE() asm volatile("" ::: "memory")

// Block = (image b, head, query row h), 256 threads = 32 px-pairs x 8 cg.
// ONLY K is LDS-staged (3 rows x 32 ch = 24 KB, gload_lds w16 with the
// verified per-channel f4-slot source rotation -> 0 bank conflicts).
// V center taps load global->regs at block start (12 b64, covered by the
// entire QK+reduce+softmax stretch); L/R taps come from neighbor lanes via
// shfl +-8 (pixel-pair neighbors are +-8 lanes). Wave-boundary pairs
// (pp&7==0/7) take a predicated direct edge load instead; image edges are
// weight-masked to 0 as before. ONE barrier per block (K-ready, 4 waves).
// 24 KB LDS + <=128 VGPR -> 4 co-resident blocks/CU at staggered phases:
// cross-block overlap hides stage latency (the round-4..10 lesson: phase
// diversity is the lever, not raw occupancy).
__global__ __launch_bounds__(256, 4) void dilate_attn(
    const float* __restrict__ q, const float* __restrict__ k,
    const float* __restrict__ v, float* __restrict__ out) {
  __shared__ float kbuf[3 * 2048];   // 24576 B: [row-slot][ch][64 px]

  const int tid = threadIdx.x;
  const int cg  = tid & 7;           // channel group (lane bits 0..2)
  const int pp  = tid >> 3;          // pixel pair 0..31

  // XCD swizzle (round-3-verified bijection): blk&7 -> XCD; each XCD owns 8
  // (b,head) combos with rows in order -> row-halo re-reads hit that L2.
  const int blk   = blockIdx.x;
  const int s     = blk >> 3;
  const int combo = ((blk & 7) << 3) | (s >> 6);  // 0..63
  const int h     = s & 63;
  const int b     = combo >> 2;
  const int head  = combo & 3;

  const size_t cb = ((size_t)b * 128 + head * 32) * 4096;
  const float* kp = k + cb;
  const float* vp = v + cb;

  int rows[3]; float rowm[3];
  #pragma unroll
  for (int r = 0; r < 3; ++r) {
    const int ry = h + 2 * (r - 1);
    const bool ok = (unsigned)ry < 64u;
    rows[r] = (ok ? ry : h) * 64;
    rowm[r] = ok ? 1.0f : 0.0f;
  }

  const int px0 = pp << 1;
  const int   txL = (pp == 0)  ? 0  : px0 - 2;   // clamped global column taps
  const int   txR = (pp == 31) ? 62 : px0 + 2;
  const float mL  = (pp == 0)  ? 0.0f : 1.0f;
  const float mR  = (pp == 31) ? 0.0f : 1.0f;
  const bool  wfirst = (pp & 7) == 0;            // first pair of its wave
  const bool  wlast  = (pp & 7) == 7;            // last pair of its wave

  // ---- q loads, raw (SCALE folded into the logit mask later, so no VALU
  //      touches these until after the barrier -> no early vmcnt wait) ----
  v2f q2[4];
  #pragma unroll
  for (int ci = 0; ci < 4; ++ci)
    q2[ci] = *(const v2f*)(q + cb + (cg * 4 + ci) * 4096 + h * 64 + px0);
  FENCE();

  // ---- stage K: 1536 f4 = 6 per thread, lane-linear dest, rotated source ----
  #pragma unroll
  for (int t = 0; t < 6; ++t) {
    const int idx = t * 256 + tid;      // f4 slot 0..1535: [slot][ch][16]
    const int sl  = idx >> 9;
    const int ch  = (idx >> 4) & 31;
    const int q4  = idx & 15;
    const int pxs = ((q4 - (ch >> 2)) & 15) << 2;
    __builtin_amdgcn_global_load_lds((gbl_v*)(kp + ch * 4096 + rows[sl] + pxs),
                                     (lds_v*)(kbuf + (idx << 2)), 16, 0, 0);
  }
  FENCE();

  // ---- V center taps -> regs (12), then predicated edge taps (12) ----
  v2f vc[3][4];
  #pragma unroll
  for (int r = 0; r < 3; ++r)
    #pragma unroll
    for (int ci = 0; ci < 4; ++ci)
      vc[r][ci] = *(const v2f*)(vp + (cg * 4 + ci) * 4096 + rows[r] + px0);
  const int eoff = wfirst ? txL : (wlast ? txR : px0);  // valid addr for all
  v2f ve[3][4];
  #pragma unroll
  for (int r = 0; r < 3; ++r)
    #pragma unroll
    for (int ci = 0; ci < 4; ++ci)
      ve[r][ci] = *(const v2f*)(vp + (cg * 4 + ci) * 4096 + rows[r] + eoff);
  FENCE();

  // ---- wait q+K only (24 newest outstanding = vc+ve); single barrier ----
  asm volatile("s_waitcnt vmcnt(24)" ::: "memory");
  __builtin_amdgcn_s_barrier();
  FENCE();

  // K tap offsets with the rotation (stored px of src p = (p + 4*cg) & 63)
  const int rot = cg << 2;
  const int tL  = (txL + rot) & 63;
  const int tC  = (px0 + rot) & 63;
  const int tR  = (txR + rot) & 63;

  // ---- QK over this thread's 4 channels (pk_fma) ----
  v2f l[9];
  #pragma unroll
  for (int i = 0; i < 9; ++i) l[i] = (v2f)(0.0f);
  #pragma unroll
  for (int r = 0; r < 3; ++r) {
    #pragma unroll
    for (int ci = 0; ci < 4; ++ci) {
      const float* kc = kbuf + r * 2048 + (cg * 4 + ci) * 64;
      l[r*3+0] = __builtin_elementwise_fma(q2[ci], *(const v2f*)(kc + tL), l[r*3+0]);
      l[r*3+1] = __builtin_elementwise_fma(q2[ci], *(const v2f*)(kc + tC), l[r*3+1]);
      l[r*3+2] = __builtin_elementwise_fma(q2[ci], *(const v2f*)(kc + tR), l[r*3+2]);
    }
  }

  // ---- reduce 8 cg-partials: xor1, xor2 via DPP; xor4 via shuffle ----
  #pragma unroll
  for (int i = 0; i < 9; ++i) { l[i].x += qperm<0xB1>(l[i].x); l[i].y += qperm<0xB1>(l[i].y); }
  #pragma unroll
  for (int i = 0; i < 9; ++i) { l[i].x += qperm<0x4E>(l[i].x); l[i].y += qperm<0x4E>(l[i].y); }
  #pragma unroll
  for (int i = 0; i < 9; ++i) {
    l[i].x += __shfl_xor(l[i].x, 4, 64);
    l[i].y += __shfl_xor(l[i].y, 4, 64);
  }

  // ---- softmax over 9; SCALE folded into the pre-exp mask multiply.
  // masked taps -> logit 0 -> e^0 = 1, matching the reference zero-pad. ----
  float msk[9];
  #pragma unroll
  for (int r = 0; r < 3; ++r) {
    msk[r*3+0] = rowm[r] * mL;
    msk[r*3+1] = rowm[r];
    msk[r*3+2] = rowm[r] * mR;
  }
  v2f sum = (v2f)(0.0f);
  #pragma unroll
  for (int i = 0; i < 9; ++i) {
    const float ms = msk[i] * SCALE;
    l[i].x = __expf(l[i].x * ms);
    l[i].y = __expf(l[i].y * ms);
    sum += l[i];
  }
  v2f rv; rv.x = 1.0f / sum.x; rv.y = 1.0f / sum.y;
  #pragma unroll
  for (int i = 0; i < 9; ++i) l[i] *= rv * msk[i];  // fold V zero-pad in

  // ---- V in regs guaranteed ----
  asm volatile("s_waitcnt vmcnt(0)" ::: "memory");

  // ---- PV: L/R taps = neighbor-lane centers (shfl +-8), edge-selected ----
  v2f o[4];
  #pragma unroll
  for (int ci = 0; ci < 4; ++ci) o[ci] = (v2f)(0.0f);
  #pragma unroll
  for (int r = 0; r < 3; ++r) {
    #pragma unroll
    for (int ci = 0; ci < 4; ++ci) {
      const v2f c = vc[r][ci];
      v2f vL, vR;
      vL.x = __shfl_up(c.x, 8, 64);
      vL.y = __shfl_up(c.y, 8, 64);
      vR.x = __shfl_down(c.x, 8, 64);
      vR.y = __shfl_down(c.y, 8, 64);
      vL = wfirst ? ve[r][ci] : vL;   // wave-boundary fixups
      vR = wlast  ? ve[r][ci] : vR;
      o[ci] = __builtin_elementwise_fma(l[r*3+0], vL, o[ci]);
      o[ci] = __builtin_elementwise_fma(l[r*3+1], c,  o[ci]);
      o[ci] = __builtin_elementwise_fma(l[r*3+2], vR, o[ci]);
    }
  }

  // ---- store: 8 px x 128B contiguous per wave-instr ----
  float* ob = out + ((size_t)(b * 64 + h) * 64 + px0) * 128 + head * 32 + cg * 4;
  *(float4*)(ob)       = make_float4(o[0].x, o[1].x, o[2].x, o[3].x);
  *(float4*)(ob + 128) = make_float4(o[0].y, o[1].y, o[2].y, o[3].y);
}
} // namespace

extern "C" void kernel_launch(void* const* d_in, const int* in_sizes, int n_in,
                              void* d_out, int out_size, void* d_ws, size_t ws_size,
                              hipStream_t stream) {
  const float* q = (const float*)d_in[0];
  const float* k = (const float*)d_in[1];
  const float* v = (const float*)d_in[2];
  float* o = (float*)d_out;
  // 16 b x 4 heads x 64 rows = 4096 blocks, 256 threads
  dilate_attn<<<dim3(4096), dim3(256), 0, stream>>>(q, k, v, o);
}